// Round 13
// baseline (442.191 us; speedup 1.0000x reference)
//
#include <hip/hip_runtime.h>
#include <hip/hip_bf16.h>

#define B_ 4096
#define T_ 2
#define S_ 4
#define E_ 128
#define NF_ 11
#define ID_ 55
#define MID_ 4
#define NG_ 6
#define SI_ 4
#define EPSf 1e-5f

typedef __attribute__((ext_vector_type(8))) short bf16x8;
typedef __attribute__((ext_vector_type(4))) float f32x4;

__device__ inline unsigned short f2bf(float f){
  unsigned int u = __float_as_uint(f);
  unsigned int r = (u + 0x7FFFu + ((u >> 16) & 1u)) >> 16;
  return (unsigned short)r;
}

// triu_indices(11, k=1) pairs, padded to 64 rows (rows 55..63: PR=PC=0, masked by iw=0)
__device__ const int PR[64]={0,0,0,0,0,0,0,0,0,0,1,1,1,1,1,1,1,1,1,2,2,2,2,2,2,2,2,3,3,3,3,3,3,3,4,4,4,4,4,4,5,5,5,5,5,6,6,6,6,7,7,7,8,8,9,0,0,0,0,0,0,0,0,0};
__device__ const int PC[64]={1,2,3,4,5,6,7,8,9,10,2,3,4,5,6,7,8,9,10,3,4,5,6,7,8,9,10,4,5,6,7,8,9,10,5,6,7,8,9,10,6,7,8,9,10,7,8,9,10,8,9,10,9,10,10,0,0,0,0,0,0,0,0,0};

// -------- prep: Wub/lWub bf16 [64 rows][136] + zero stats accumulators ------
__global__ void k_prep(const float* __restrict__ gW, const float* __restrict__ lgW,
                       const float* __restrict__ sbW, const float* __restrict__ lsbW,
                       unsigned short* __restrict__ Wub, unsigned short* __restrict__ lWub,
                       float* __restrict__ sm1, float* __restrict__ slt,
                       float* __restrict__ sh1, float* __restrict__ sh2,
                       float* __restrict__ sh3){
  int k = blockIdx.x*256 + threadIdx.x;
  if (k < 8704){
    int o = k / 136, e = k % 136;
    float v = 0.f, lv = 0.f;
    if (e < 128){
      if (o < 48){ v = gW[o*132 + 4 + e]; lv = lgW[o*132 + 4 + e]; }
      else if (o < 62){ v = sbW[(o-48)*128 + e]; lv = lsbW[(o-48)*128 + e]; }
    }
    Wub[k] = f2bf(v);
    lWub[k] = f2bf(lv);
  }
  if (k < 880)  sm1[k] = 0.f;
  if (k < 1408) slt[k] = 0.f;
  if (k < 1280) sh1[k] = 0.f;
  if (k < 128)  sh2[k] = 0.f;
  if (k < 32)   sh3[k] = 0.f;
}

// -------- moe12: MFMA moe1 + MFMA moe2, in-kernel field gen, lt1 stats ------
// (structure identical to R12's validated kernel; adds banked lt1-stat atomics)
__global__ __launch_bounds__(256) void k_moe12(
    const int* __restrict__ cat, const float* __restrict__ num,
    const float* __restrict__ embT, const float* __restrict__ linT,
    const float* __restrict__ uW, const float* __restrict__ ub,
    const float* __restrict__ iW, const float* __restrict__ ib,
    const float* __restrict__ ulW, const float* __restrict__ ulb,
    const float* __restrict__ ilW, const float* __restrict__ ilb,
    const float* __restrict__ scen_emb, const float* __restrict__ task_emb,
    const float* __restrict__ st_w, const float* __restrict__ interact_w,
    const float* __restrict__ sb_b,
    const float* __restrict__ shexp_W, const float* __restrict__ shexp_b,
    const float* __restrict__ spexp_W, const float* __restrict__ spexp_b,
    const float* __restrict__ gate_W, const float* __restrict__ gate_b,
    const unsigned short* __restrict__ Wub,
    const float* __restrict__ lsb_b,
    const float* __restrict__ lshexp_W, const float* __restrict__ lshexp_b,
    const float* __restrict__ lspexp_W, const float* __restrict__ lspexp_b,
    const float* __restrict__ lgate_W, const float* __restrict__ lgate_b,
    const float* __restrict__ ltower_W, const float* __restrict__ ltower_b,
    const unsigned short* __restrict__ lWub,
    float* __restrict__ w_g, float* __restrict__ lt1, float* __restrict__ slt)
{
  __shared__ float sm[6595];
  float* s_fld = sm;           // 11 x 132
  float* s_stig= sm + 1452;    // 48
  unsigned short* s_peb = (unsigned short*)(sm + 1500);  // 55 x 136 bf16
  float* s_C   = sm + 1500;    // overlay: 64 x 65
  float* s_sh  = sm + 5660;    // overlay: 55 x 17
  unsigned short* s_lfb = (unsigned short*)(sm + 1500); // 16 x 136 bf16
  float* m2_C   = sm + 2588;   // 12 x 65
  float* m2_sh  = sm + 3368;   // 11 x 17
  float* m2_stig= sm + 3555;   // 48
  float* m2_w   = sm + 3603;   // 8 x 44
  const int tid = threadIdx.x, b = blockIdx.x;
  const int* cb = cat + (size_t)b*10;
  const int scen = cb[0];
  const int e = tid & 127, half = tid >> 7;
  const int w = tid >> 6, lane = tid & 63;
  const int cg = lane >> 4, cc = lane & 15;

  // ---- stage: fields -> s_fld, stig ----
  if (half == 0){
    for (int j = 0; j < 9; j += 2){
      int id = cb[1+j] + j*1000;
      s_fld[j*132 + e] = embT[(size_t)id*128 + e];
    }
    float a0 = ub[e];
    for (int k = 0; k < 23; ++k) a0 += num[(size_t)b*63 + k] * uW[e*23 + k];
    s_fld[9*132 + e] = a0;
  } else {
    for (int j = 1; j < 9; j += 2){
      int id = cb[1+j] + j*1000;
      s_fld[j*132 + e] = embT[(size_t)id*128 + e];
    }
    float a2 = ib[e];
    for (int k = 0; k < 40; ++k) a2 += num[(size_t)b*63 + 23 + k] * iW[e*40 + k];
    s_fld[10*132 + e] = a2;
  }
  if (tid < 48){
    int t = (tid/6)%T_;
    float stw = st_w[t*S_ + scen];
    float acc = gate_b[tid];
    for (int i = 0; i < 4; ++i){
      float sti = scen_emb[scen*4+i] * task_emb[t*4+i] * stw;
      acc += sti * gate_W[tid*132 + i];
    }
    s_stig[tid] = acc;
  }
  __syncthreads();

  // ---- build pe bf16 (iw applied in epilogue) ----
  for (int idx = tid; idx < 1760; idx += 256){
    int row = idx >> 5, q = idx & 31;
    float4 x = *(const float4*)&s_fld[PR[row]*132 + q*4];
    float4 y = *(const float4*)&s_fld[PC[row]*132 + q*4];
    ushort4 o;
    o.x = f2bf(x.x*y.x); o.y = f2bf(x.y*y.y); o.z = f2bf(x.z*y.z); o.w = f2bf(x.w*y.w);
    *(ushort4*)&s_peb[row*136 + q*4] = o;
  }
  __syncthreads();

  // ---- MFMA GEMM: C[64][64] = pe x Wu^T ----
  f32x4 acc0 = {0.f,0.f,0.f,0.f}, acc1 = acc0, acc2 = acc0, acc3 = acc0;
  {
    const int kb = cg * 8;
    #pragma unroll
    for (int ks = 0; ks < 4; ++ks){
      int ko = ks*32 + kb;
      bf16x8 bfr = *(const bf16x8*)&Wub[(w*16 + cc)*136 + ko];
      bf16x8 a0 = *(const bf16x8*)&s_peb[( 0 + cc)*136 + ko];
      bf16x8 a1 = *(const bf16x8*)&s_peb[(16 + cc)*136 + ko];
      bf16x8 a2 = *(const bf16x8*)&s_peb[(32 + cc)*136 + ko];
      bf16x8 a3 = *(const bf16x8*)&s_peb[(48 + cc)*136 + ko];
      acc0 = __builtin_amdgcn_mfma_f32_16x16x32_bf16(a0, bfr, acc0, 0, 0, 0);
      acc1 = __builtin_amdgcn_mfma_f32_16x16x32_bf16(a1, bfr, acc1, 0, 0, 0);
      acc2 = __builtin_amdgcn_mfma_f32_16x16x32_bf16(a2, bfr, acc2, 0, 0, 0);
      acc3 = __builtin_amdgcn_mfma_f32_16x16x32_bf16(a3, bfr, acc3, 0, 0, 0);
    }
  }
  __syncthreads();
  {
    const int col = w*16 + cc;
    const float bias = (col < 48) ? s_stig[col] : ((col < 62) ? sb_b[col-48] : 0.f);
    #pragma unroll
    for (int r = 0; r < 4; ++r){
      int row0 = cg*4 + r;
      float v0 = (r==0)?acc0.x:((r==1)?acc0.y:((r==2)?acc0.z:acc0.w));
      float v1 = (r==0)?acc1.x:((r==1)?acc1.y:((r==2)?acc1.z:acc1.w));
      float v2 = (r==0)?acc2.x:((r==1)?acc2.y:((r==2)?acc2.z:acc2.w));
      float v3 = (r==0)?acc3.x:((r==1)?acc3.y:((r==2)?acc3.z:acc3.w));
      s_C[(row0     )*65 + col] = v0*interact_w[row0     ] + bias;
      s_C[(row0 + 16)*65 + col] = v1*interact_w[row0 + 16] + bias;
      s_C[(row0 + 32)*65 + col] = v2*interact_w[row0 + 32] + bias;
      if (row0 + 48 < 55)
        s_C[(row0 + 48)*65 + col] = v3*interact_w[row0 + 48] + bias;
    }
  }
  __syncthreads();
  for (int o = tid; o < 880; o += 256){
    int f = o >> 4, j = o & 15;
    float acc = shexp_b[j];
    const float* ein = &s_C[f*65 + 48];
    const float* wp = &shexp_W[j*14];
    for (int i = 0; i < 14; ++i) acc += ein[i] * wp[i];
    s_sh[f*17 + j] = acc;
  }
  __syncthreads();
  for (int task = tid; task < 440; task += 256){
    int st = task / 55, f = task % 55;
    float ein[14];
    for (int i = 0; i < 14; ++i) ein[i] = s_C[f*65 + 48 + i];
    float lg[6], mx = -1e30f;
    for (int g = 0; g < 6; ++g){ lg[g] = s_C[f*65 + st*6 + g]; mx = fmaxf(mx, lg[g]); }
    float sum = 0.f;
    for (int g = 0; g < 6; ++g){ lg[g] = __expf(lg[g]-mx); sum += lg[g]; }
    float inv = 1.f/sum;
    float wv[4] = {0,0,0,0};
    for (int g = 0; g < 4; ++g){
      float gg = lg[g]*inv;
      for (int m = 0; m < 4; ++m) wv[m] += gg * s_sh[f*17 + g*4 + m];
    }
    for (int ee = 0; ee < 2; ++ee){
      float gg = lg[4+ee]*inv;
      for (int m = 0; m < 4; ++m){
        float acc = spexp_b[(st*2+ee)*4+m];
        const float* wp = spexp_W + ((st*2+ee)*4+m)*14;
        for (int i = 0; i < 14; ++i) acc += ein[i] * wp[i];
        wv[m] += gg*acc;
      }
    }
    float4 o4; o4.x = wv[0]; o4.y = wv[1]; o4.z = wv[2]; o4.w = wv[3];
    *(float4*)&w_g[((size_t)b*8 + st)*224 + f*4] = o4;
  }
  if (tid < 8){
    float4 z = {0,0,0,0};
    *(float4*)&w_g[((size_t)b*8 + tid)*224 + 220] = z;
  }
  __syncthreads();

  // ---- moe2: gather lfields as bf16 + stig2 ----
  if (half == 0){
    for (int j = 0; j < 9; j += 2){
      int id = cb[1+j] + j*1000;
      s_lfb[j*136 + e] = f2bf(linT[(size_t)id*128 + e]);
    }
    float a1 = ulb[e];
    for (int k = 0; k < 23; ++k) a1 += num[(size_t)b*63 + k] * ulW[e*23 + k];
    s_lfb[9*136 + e] = f2bf(a1);
  } else {
    for (int j = 1; j < 9; j += 2){
      int id = cb[1+j] + j*1000;
      s_lfb[j*136 + e] = f2bf(linT[(size_t)id*128 + e]);
    }
    float a3 = ilb[e];
    for (int k = 0; k < 40; ++k) a3 += num[(size_t)b*63 + 23 + k] * ilW[e*40 + k];
    s_lfb[10*136 + e] = f2bf(a3);
  }
  if (tid < 48){
    int t = (tid/6)%T_;
    float stw = st_w[t*S_ + scen];
    float acc = lgate_b[tid];
    for (int i = 0; i < 4; ++i){
      float sti = scen_emb[scen*4+i] * task_emb[t*4+i] * stw;
      acc += sti * lgate_W[tid*132 + i];
    }
    m2_stig[tid] = acc;
  }
  __syncthreads();
  {
    f32x4 macc = {0.f,0.f,0.f,0.f};
    const int kb = cg * 8;
    #pragma unroll
    for (int ks = 0; ks < 4; ++ks){
      int ko = ks*32 + kb;
      bf16x8 bfr = *(const bf16x8*)&lWub[(w*16 + cc)*136 + ko];
      bf16x8 av  = *(const bf16x8*)&s_lfb[cc*136 + ko];
      macc = __builtin_amdgcn_mfma_f32_16x16x32_bf16(av, bfr, macc, 0, 0, 0);
    }
    const int col = w*16 + cc;
    const float bias = (col < 48) ? m2_stig[col] : ((col < 62) ? lsb_b[col-48] : 0.f);
    #pragma unroll
    for (int r = 0; r < 4; ++r){
      int row = cg*4 + r;
      if (row < 11){
        float v = (r==0)?macc.x:((r==1)?macc.y:((r==2)?macc.z:macc.w));
        m2_C[row*65 + col] = v + bias;
      }
    }
  }
  __syncthreads();
  if (tid < 176){
    int f = tid >> 4, j = tid & 15;
    float acc = lshexp_b[j];
    const float* ein = &m2_C[f*65 + 48];
    for (int i = 0; i < 14; ++i) acc += ein[i] * lshexp_W[j*14+i];
    m2_sh[f*17 + j] = acc;
  }
  __syncthreads();
  if (tid < 88){
    int st = tid / 11, f = tid % 11;
    float ein[14];
    for (int i = 0; i < 14; ++i) ein[i] = m2_C[f*65 + 48 + i];
    float lg[6], mx = -1e30f;
    for (int g = 0; g < 6; ++g){ lg[g] = m2_C[f*65 + st*6 + g]; mx = fmaxf(mx, lg[g]); }
    float sum = 0.f;
    for (int g = 0; g < 6; ++g){ lg[g] = __expf(lg[g]-mx); sum += lg[g]; }
    float inv = 1.f/sum;
    float wv[4] = {0,0,0,0};
    for (int g = 0; g < 4; ++g){
      float gg = lg[g]*inv;
      for (int m = 0; m < 4; ++m) wv[m] += gg * m2_sh[f*17 + g*4 + m];
    }
    for (int ee = 0; ee < 2; ++ee){
      float gg = lg[4+ee]*inv;
      for (int m = 0; m < 4; ++m){
        float acc = lspexp_b[(st*2+ee)*4+m];
        const float* wp = lspexp_W + ((st*2+ee)*4+m)*14;
        for (int i = 0; i < 14; ++i) acc += ein[i] * wp[i];
        wv[m] += gg*acc;
      }
    }
    float4 o4; o4.x = wv[0]; o4.y = wv[1]; o4.z = wv[2]; o4.w = wv[3];
    *(float4*)&m2_w[st*44 + f*4] = o4;
  }
  __syncthreads();
  if (tid < 88){
    int st = tid / 11, oo = tid % 11;
    float acc = ltower_b[st*11+oo];
    const float* tw = ltower_W + (st*11+oo)*44;
    const float* wp = m2_w + st*44;
    for (int i = 0; i < 44; ++i) acc += wp[i] * tw[i];
    lt1[(size_t)(st*11+oo)*B_ + b] = acc;
    // banked lt1 stats (row index == tid)
    float* bank = slt + ((size_t)(b & 7)*88 + tid)*2;
    atomicAdd(&bank[0], acc);
    atomicAdd(&bank[1], acc*acc);
  }
}

// -------- mask batch GEMM + m1 row-stat accumulation ------------------------
__global__ __launch_bounds__(256) void k_mask(
    const float* __restrict__ w_g, const float* __restrict__ mask_W,
    const float* __restrict__ mask_b, float* __restrict__ m1,
    float* __restrict__ sm1)
{
  __shared__ float s_mw[56*116];
  __shared__ float s_wb[64*116];
  const int tid = threadIdx.x;
  const int st = blockIdx.x >> 6, bt = blockIdx.x & 63;
  const int b0 = bt*64;
  const int btl = tid & 15, ot = tid >> 4;   // ot<14 active
  float acc[4][4];
  for (int c = 0; c < 4; ++c) for (int j = 0; j < 4; ++j) acc[c][j] = 0.f;

  for (int kc = 0; kc < 2; ++kc){
    __syncthreads();
    for (int idx = tid; idx < 64*112; idx += 256){
      int r = idx / 112, k = idx % 112;
      s_wb[r*116 + k] = w_g[((size_t)(b0+r)*8 + st)*224 + kc*112 + k];
    }
    for (int idx = tid; idx < 56*112; idx += 256){
      int r = idx / 112, k = idx % 112;
      int kg = kc*112 + k;
      s_mw[r*116 + k] = (r < 55 && kg < 220) ? mask_W[((size_t)st*55 + r)*220 + kg] : 0.f;
    }
    __syncthreads();
    if (ot < 14){
      for (int k4 = 0; k4 < 112; k4 += 4){
        float4 a[4], wb[4];
        for (int c = 0; c < 4; ++c) a[c]  = *(float4*)&s_mw[(ot*4+c)*116 + k4];
        for (int j = 0; j < 4; ++j) wb[j] = *(float4*)&s_wb[(btl*4+j)*116 + k4];
        for (int c = 0; c < 4; ++c)
          for (int j = 0; j < 4; ++j)
            acc[c][j] += a[c].x*wb[j].x + a[c].y*wb[j].y + a[c].z*wb[j].z + a[c].w*wb[j].w;
      }
    }
  }
  if (ot < 14){
    for (int c = 0; c < 4; ++c){
      int row = ot*4 + c;
      if (row < 55){
        float mb = mask_b[st*55 + row];
        float4 v; v.x = acc[c][0]+mb; v.y = acc[c][1]+mb; v.z = acc[c][2]+mb; v.w = acc[c][3]+mb;
        *(float4*)&m1[(size_t)(st*55+row)*B_ + b0 + btl*4] = v;
        // per-row partial stats over this block's 64 b-values
        float s = v.x + v.y + v.z + v.w;
        float s2 = v.x*v.x + v.y*v.y + v.z*v.z + v.w*v.w;
        for (int d = 8; d > 0; d >>= 1){
          s  += __shfl_down(s, d, 16);
          s2 += __shfl_down(s2, d, 16);
        }
        if (btl == 0){
          atomicAdd(&sm1[(st*55+row)*2],     s);
          atomicAdd(&sm1[(st*55+row)*2 + 1], s2);
        }
      }
    }
  }
}

// -------- interlinf+last1: inline stat finalize + h1 stat accumulation ------
__global__ __launch_bounds__(128) void k_interlinf(
    const int* __restrict__ cat, const float* __restrict__ num,
    const float* __restrict__ embT, const float* __restrict__ linT,
    const float* __restrict__ uW, const float* __restrict__ ub,
    const float* __restrict__ iW, const float* __restrict__ ib,
    const float* __restrict__ ulW, const float* __restrict__ ulb,
    const float* __restrict__ ilW, const float* __restrict__ ilb,
    const float* __restrict__ m1, const float* __restrict__ sm1,
    const float* __restrict__ lt1, const float* __restrict__ slt,
    const float* __restrict__ att_W, const float* __restrict__ interact_w,
    const float* __restrict__ bias_p,
    const float* __restrict__ W1, const float* __restrict__ b1,
    float* __restrict__ h1, float* __restrict__ sh1)
{
  __shared__ float s_fld[NF_*E_];
  __shared__ float s_lf[NF_*E_];
  __shared__ float s_co[110];
  __shared__ float s_lw[22];
  __shared__ float s_h[512];
  const int b = blockIdx.x, e = threadIdx.x;
  const int* cb = cat + (size_t)b*10;
  const int scen = cb[0];

  for (int j = 0; j < 9; ++j){
    int id = cb[1+j] + j*1000;
    s_fld[j*E_+e] = embT[(size_t)id*128 + e];
    s_lf[j*E_+e]  = linT[(size_t)id*128 + e];
  }
  {
    float a0 = ub[e], a1 = ulb[e];
    for (int k = 0; k < 23; ++k){ float x = num[(size_t)b*63 + k]; a0 += x*uW[e*23+k]; a1 += x*ulW[e*23+k]; }
    s_fld[9*E_+e] = a0; s_lf[9*E_+e] = a1;
    float a2 = ib[e], a3 = ilb[e];
    for (int k = 0; k < 40; ++k){ float x = num[(size_t)b*63 + 23 + k]; a2 += x*iW[e*40+k]; a3 += x*ilW[e*40+k]; }
    s_fld[10*E_+e] = a2; s_lf[10*E_+e] = a3;
  }
  if (e < 110){
    int t = e/55, f = e%55, row = (scen*T_+t)*55 + f;
    float sum = sm1[row*2], ssq = sm1[row*2+1];
    float mean = sum*(1.f/B_);
    float var  = ssq*(1.f/B_) - mean*mean;
    float rsq  = rsqrtf(fmaxf(var, 0.f) + EPSf);
    float v = (m1[(size_t)row*B_+b] - mean) * rsq;
    v = fmaxf(tanhf(v), 0.f);
    s_co[e] = v * att_W[(scen*T_+t)*55 + f];
  }
  if (e < 22){
    int t = e/11, f = e%11, row = (scen*T_+t)*11 + f;
    float sum = 0.f, ssq = 0.f;
    for (int bk = 0; bk < 8; ++bk){
      sum += slt[((size_t)bk*88 + row)*2];
      ssq += slt[((size_t)bk*88 + row)*2 + 1];
    }
    float mean = sum*(1.f/B_);
    float var  = ssq*(1.f/B_) - mean*mean;
    float rsq  = rsqrtf(fmaxf(var, 0.f) + EPSf);
    s_lw[e] = (lt1[(size_t)row*B_+b] - mean) * rsq;
  }
  __syncthreads();
  if (e < 2){
    int t = e; float mx = -1e30f;
    for (int f = 0; f < 11; ++f) mx = fmaxf(mx, s_lw[t*11+f]);
    float sum = 0.f;
    for (int f = 0; f < 11; ++f){ float x = __expf(s_lw[t*11+f]-mx); s_lw[t*11+f] = x; sum += x; }
    float inv = 1.f/sum;
    for (int f = 0; f < 11; ++f) s_lw[t*11+f] *= inv;
  }
  __syncthreads();
  {
    float a0 = 0.f, a1 = 0.f;
    for (int f = 0; f < 55; ++f){
      float pe = s_fld[PR[f]*E_+e] * s_fld[PC[f]*E_+e] * interact_w[f];
      a0 += s_co[f]*pe; a1 += s_co[55+f]*pe;
    }
    s_h[0*256 + e] = a0;
    s_h[1*256 + e] = a1;
  }
  for (int t = 0; t < 2; ++t){
    float acc = bias_p[(size_t)(t*S_+scen)*E_ + e];
    for (int f = 0; f < 11; ++f) acc += s_lw[t*11+f] * s_lf[f*E_+e];
    s_h[t*256 + 128 + e] = acc;
  }
  __syncthreads();
  if (e < 80){
    int t = e / 40, o = e % 40;
    float acc = b1[t*40 + o];
    const float4* wr = (const float4*)(W1 + (size_t)(t*40 + o)*256);
    const float4* hh = (const float4*)(s_h + t*256);
    for (int i = 0; i < 64; ++i){
      float4 w = wr[i], h = hh[i];
      acc += h.x*w.x; acc += h.y*w.y; acc += h.z*w.z; acc += h.w*w.w;
    }
    h1[(size_t)(t*40 + o)*B_ + b] = acc;
    float* bank = sh1 + ((size_t)(b & 7)*80 + t*40 + o)*2;
    atomicAdd(&bank[0], acc);
    atomicAdd(&bank[1], acc*acc);
  }
}

// -------- last2: inline st1 finalize, h2 + h2-stat accumulation -------------
__global__ __launch_bounds__(256) void k_last2(const float* __restrict__ h1, const float* __restrict__ sh1,
    const float* __restrict__ W2, const float* __restrict__ b2v,
    float* __restrict__ h2, float* __restrict__ sh2){
  int bz = blockIdx.x, t = bz/16, bc = bz%16, tid = threadIdx.x, b = bc*256 + tid;
  __shared__ float s_w2[1280];
  __shared__ float s_st1[160];   // [row][mean, rsq]
  for (int k = tid; k < 1280; k += 256) s_w2[k] = W2[t*1280 + k];
  if (tid < 80){
    float sum = 0.f, ssq = 0.f;
    for (int bk = 0; bk < 8; ++bk){
      sum += sh1[((size_t)bk*80 + tid)*2];
      ssq += sh1[((size_t)bk*80 + tid)*2 + 1];
    }
    float mean = sum*(1.f/B_);
    float var  = ssq*(1.f/B_) - mean*mean;
    s_st1[tid*2] = mean;
    s_st1[tid*2+1] = rsqrtf(fmaxf(var, 0.f) + EPSf);
  }
  __syncthreads();
  float hv[40];
  for (int i = 0; i < 40; ++i){
    int row = t*40 + i;
    hv[i] = fmaxf((h1[(size_t)row*B_+b] - s_st1[row*2]) * s_st1[row*2+1], 0.f);
  }
  for (int o = 0; o < 32; ++o){
    float acc = b2v[t*32+o];
    for (int i = 0; i < 40; ++i) acc += hv[i] * s_w2[o*40+i];
    h2[(size_t)(t*32+o)*B_ + b] = acc;
    float v = acc, v2 = acc*acc;
    for (int d = 32; d > 0; d >>= 1){ v += __shfl_down(v, d); v2 += __shfl_down(v2, d); }
    if ((tid & 63) == 0){
      atomicAdd(&sh2[(t*32+o)*2],     v);
      atomicAdd(&sh2[(t*32+o)*2 + 1], v2);
    }
  }
}

// -------- last3: inline st2 finalize, h3 + h3-stat accumulation -------------
__global__ __launch_bounds__(256) void k_last3(const float* __restrict__ h2, const float* __restrict__ sh2,
    const float* __restrict__ W3, const float* __restrict__ b3v,
    float* __restrict__ h3, float* __restrict__ sh3){
  int bz = blockIdx.x, t = bz/16, bc = bz%16, tid = threadIdx.x, b = bc*256 + tid;
  __shared__ float s_w3[256];
  __shared__ float s_st2[128];
  if (tid < 256) s_w3[tid] = W3[t*256 + tid];
  if (tid < 64){
    float sum = sh2[tid*2], ssq = sh2[tid*2+1];
    float mean = sum*(1.f/B_);
    float var  = ssq*(1.f/B_) - mean*mean;
    s_st2[tid*2] = mean;
    s_st2[tid*2+1] = rsqrtf(fmaxf(var, 0.f) + EPSf);
  }
  __syncthreads();
  float hv[32];
  for (int i = 0; i < 32; ++i){
    int row = t*32 + i;
    hv[i] = fmaxf((h2[(size_t)row*B_+b] - s_st2[row*2]) * s_st2[row*2+1], 0.f);
  }
  for (int o = 0; o < 8; ++o){
    float acc = b3v[t*8+o];
    for (int i = 0; i < 32; ++i) acc += hv[i] * s_w3[o*32+i];
    h3[(size_t)(t*8+o)*B_ + b] = acc;
    float v = acc, v2 = acc*acc;
    for (int d = 32; d > 0; d >>= 1){ v += __shfl_down(v, d); v2 += __shfl_down(v2, d); }
    if ((tid & 63) == 0){
      atomicAdd(&sh3[(t*8+o)*2],     v);
      atomicAdd(&sh3[(t*8+o)*2 + 1], v2);
    }
  }
}

// -------- out: inline st3 finalize + sigmoid --------------------------------
__global__ __launch_bounds__(256) void k_out(const float* __restrict__ h3, const float* __restrict__ sh3,
    const float* __restrict__ W4, const float* __restrict__ b4v, float* __restrict__ out){
  __shared__ float s_st3[32];
  int tid = threadIdx.x;
  if (tid < 16){
    float sum = sh3[tid*2], ssq = sh3[tid*2+1];
    float mean = sum*(1.f/B_);
    float var  = ssq*(1.f/B_) - mean*mean;
    s_st3[tid*2] = mean;
    s_st3[tid*2+1] = rsqrtf(fmaxf(var, 0.f) + EPSf);
  }
  __syncthreads();
  int idx = blockIdx.x*256 + tid;
  int t = idx / B_, b = idx % B_;
  float acc = b4v[t];
  for (int i = 0; i < 8; ++i){
    int row = t*8 + i;
    float v = fmaxf((h3[(size_t)row*B_+b] - s_st3[row*2]) * s_st3[row*2+1], 0.f);
    acc += v * W4[t*8+i];
  }
  out[idx] = 1.f/(1.f + __expf(-acc));
}

extern "C" void kernel_launch(void* const* d_in, const int* in_sizes, int n_in,
                              void* d_out, int out_size, void* d_ws, size_t ws_size,
                              hipStream_t stream)
{
  const int*   cat      = (const int*)  d_in[0];
  const float* num      = (const float*)d_in[1];
  const float* embT     = (const float*)d_in[2];
  const float* linT     = (const float*)d_in[3];
  const float* uW = (const float*)d_in[4];  const float* ub = (const float*)d_in[5];
  const float* iW = (const float*)d_in[6];  const float* ib = (const float*)d_in[7];
  const float* ulW = (const float*)d_in[8]; const float* ulb = (const float*)d_in[9];
  const float* ilW = (const float*)d_in[10];const float* ilb = (const float*)d_in[11];
  const float* scen_emb = (const float*)d_in[12];
  const float* task_emb = (const float*)d_in[13];
  const float* st_w     = (const float*)d_in[14];
  const float* interact_w=(const float*)d_in[15];
  const float* sbW = (const float*)d_in[16]; const float* sbb = (const float*)d_in[17];
  const float* lsbW = (const float*)d_in[18];const float* lsbb = (const float*)d_in[19];
  const float* shW = (const float*)d_in[20]; const float* shb = (const float*)d_in[21];
  const float* spW = (const float*)d_in[22]; const float* spb = (const float*)d_in[23];
  const float* lshW = (const float*)d_in[24];const float* lshb = (const float*)d_in[25];
  const float* lspW = (const float*)d_in[26];const float* lspb = (const float*)d_in[27];
  const float* gW = (const float*)d_in[28];  const float* gb = (const float*)d_in[29];
  const float* lgW = (const float*)d_in[30]; const float* lgb = (const float*)d_in[31];
  const float* mW = (const float*)d_in[32];  const float* mb = (const float*)d_in[33];
  const float* attW = (const float*)d_in[34];
  const float* ltW = (const float*)d_in[35]; const float* ltb = (const float*)d_in[36];
  const float* biasP = (const float*)d_in[37];
  const float* W1 = (const float*)d_in[38];  const float* b1 = (const float*)d_in[39];
  const float* W2 = (const float*)d_in[40];  const float* b2v = (const float*)d_in[41];
  const float* W3 = (const float*)d_in[42];  const float* b3v = (const float*)d_in[43];
  const float* W4 = (const float*)d_in[44];  const float* b4v = (const float*)d_in[45];
  float* out = (float*)d_out;

  float* ws = (float*)d_ws;
  size_t o = 0;
  float* Wub  = ws + o; o += 4352;   // bf16 64x136 as ushorts
  float* lWub = ws + o; o += 4352;   // bf16 64x136 as ushorts
  float* w_g  = ws + o; o += (size_t)B_*8*224;
  float* m1   = ws + o; o += (size_t)440*B_;
  float* sm1  = ws + o; o += 880;
  float* lt1  = ws + o; o += (size_t)88*B_;
  float* slt  = ws + o; o += 1408;   // 8 banks x 88 x 2
  float* h1   = ws + o; o += (size_t)80*B_;
  float* sh1  = ws + o; o += 1280;   // 8 banks x 80 x 2
  float* h2   = ws + o; o += (size_t)64*B_;
  float* sh2  = ws + o; o += 128;
  float* h3   = ws + o; o += (size_t)16*B_;
  float* sh3  = ws + o; o += 32;

  k_prep<<<34, 256, 0, stream>>>(gW, lgW, sbW, lsbW, (unsigned short*)Wub, (unsigned short*)lWub,
                                 sm1, slt, sh1, sh2, sh3);
  k_moe12<<<B_, 256, 0, stream>>>(cat, num, embT, linT, uW, ub, iW, ib, ulW, ulb, ilW, ilb,
                                  scen_emb, task_emb, st_w, interact_w, sbb, shW, shb,
                                  spW, spb, gW, gb, (const unsigned short*)Wub,
                                  lsbb, lshW, lshb, lspW, lspb, lgW, lgb, ltW, ltb,
                                  (const unsigned short*)lWub, w_g, lt1, slt);
  k_mask<<<512, 256, 0, stream>>>(w_g, mW, mb, m1, sm1);
  k_interlinf<<<B_, 128, 0, stream>>>(cat, num, embT, linT, uW, ub, iW, ib, ulW, ulb, ilW, ilb,
                                      m1, sm1, lt1, slt, attW, interact_w, biasP,
                                      W1, b1, h1, sh1);
  k_last2<<<32, 256, 0, stream>>>(h1, sh1, W2, b2v, h2, sh2);
  k_last3<<<32, 256, 0, stream>>>(h2, sh2, W3, b3v, h3, sh3);
  k_out<<<32, 256, 0, stream>>>(h3, sh3, W4, b4v, out);
}

// Round 14
// 369.067 us; speedup vs baseline: 1.1981x; 1.1981x over previous
//
#include <hip/hip_runtime.h>
#include <hip/hip_bf16.h>

#define B_ 4096
#define T_ 2
#define S_ 4
#define E_ 128
#define NF_ 11
#define ID_ 55
#define MID_ 4
#define NG_ 6
#define SI_ 4
#define EPSf 1e-5f

typedef __attribute__((ext_vector_type(8))) short bf16x8;
typedef __attribute__((ext_vector_type(4))) float f32x4;

__device__ inline unsigned short f2bf(float f){
  unsigned int u = __float_as_uint(f);
  unsigned int r = (u + 0x7FFFu + ((u >> 16) & 1u)) >> 16;
  return (unsigned short)r;
}

// triu_indices(11, k=1) pairs, padded to 64 rows (rows 55..63: PR=PC=0, masked by iw=0)
__device__ const int PR[64]={0,0,0,0,0,0,0,0,0,0,1,1,1,1,1,1,1,1,1,2,2,2,2,2,2,2,2,3,3,3,3,3,3,3,4,4,4,4,4,4,5,5,5,5,5,6,6,6,6,7,7,7,8,8,9,0,0,0,0,0,0,0,0,0};
__device__ const int PC[64]={1,2,3,4,5,6,7,8,9,10,2,3,4,5,6,7,8,9,10,3,4,5,6,7,8,9,10,4,5,6,7,8,9,10,5,6,7,8,9,10,6,7,8,9,10,7,8,9,10,8,9,10,9,10,10,0,0,0,0,0,0,0,0,0};

// -------- prep: Wub/lWub bf16 [64][136] + mWb bf16 [8][64][224] -------------
// Wub rows 0-47 gate E-part, 48-61 sb_W, rest 0. mWb rows>=55 / k>=220 zero.
__global__ void k_prep(const float* __restrict__ gW, const float* __restrict__ lgW,
                       const float* __restrict__ sbW, const float* __restrict__ lsbW,
                       const float* __restrict__ mW,
                       unsigned short* __restrict__ Wub, unsigned short* __restrict__ lWub,
                       unsigned short* __restrict__ mWb){
  int k = blockIdx.x*256 + threadIdx.x;
  if (k < 8704){
    int o = k / 136, e = k % 136;
    float v = 0.f, lv = 0.f;
    if (e < 128){
      if (o < 48){ v = gW[o*132 + 4 + e]; lv = lgW[o*132 + 4 + e]; }
      else if (o < 62){ v = sbW[(o-48)*128 + e]; lv = lsbW[(o-48)*128 + e]; }
    }
    Wub[k] = f2bf(v);
    lWub[k] = f2bf(lv);
  }
  if (k < 114688){   // 8 st x 64 rows x 224 k
    int st = k / (64*224), rem = k % (64*224);
    int r = rem / 224, kk = rem % 224;
    float v = (r < 55 && kk < 220) ? mW[((size_t)st*55 + r)*220 + kk] : 0.f;
    mWb[k] = f2bf(v);
  }
}

// -------- moe12: MFMA moe1 + MFMA moe2, in-kernel field generation ----------
// Identical to R12's validated kernel except w_g is written as bf16.
__global__ __launch_bounds__(256) void k_moe12(
    const int* __restrict__ cat, const float* __restrict__ num,
    const float* __restrict__ embT, const float* __restrict__ linT,
    const float* __restrict__ uW, const float* __restrict__ ub,
    const float* __restrict__ iW, const float* __restrict__ ib,
    const float* __restrict__ ulW, const float* __restrict__ ulb,
    const float* __restrict__ ilW, const float* __restrict__ ilb,
    const float* __restrict__ scen_emb, const float* __restrict__ task_emb,
    const float* __restrict__ st_w, const float* __restrict__ interact_w,
    const float* __restrict__ sb_b,
    const float* __restrict__ shexp_W, const float* __restrict__ shexp_b,
    const float* __restrict__ spexp_W, const float* __restrict__ spexp_b,
    const float* __restrict__ gate_W, const float* __restrict__ gate_b,
    const unsigned short* __restrict__ Wub,
    const float* __restrict__ lsb_b,
    const float* __restrict__ lshexp_W, const float* __restrict__ lshexp_b,
    const float* __restrict__ lspexp_W, const float* __restrict__ lspexp_b,
    const float* __restrict__ lgate_W, const float* __restrict__ lgate_b,
    const float* __restrict__ ltower_W, const float* __restrict__ ltower_b,
    const unsigned short* __restrict__ lWub,
    unsigned short* __restrict__ w_gb, float* __restrict__ lt1)
{
  __shared__ float sm[6595];
  float* s_fld = sm;           // 11 x 132
  float* s_stig= sm + 1452;    // 48
  unsigned short* s_peb = (unsigned short*)(sm + 1500);  // 55 x 136 bf16
  float* s_C   = sm + 1500;    // overlay: 64 x 65
  float* s_sh  = sm + 5660;    // overlay: 55 x 17
  unsigned short* s_lfb = (unsigned short*)(sm + 1500); // 16 x 136 bf16
  float* m2_C   = sm + 2588;   // 12 x 65
  float* m2_sh  = sm + 3368;   // 11 x 17
  float* m2_stig= sm + 3555;   // 48
  float* m2_w   = sm + 3603;   // 8 x 44
  const int tid = threadIdx.x, b = blockIdx.x;
  const int* cb = cat + (size_t)b*10;
  const int scen = cb[0];
  const int e = tid & 127, half = tid >> 7;
  const int w = tid >> 6, lane = tid & 63;
  const int cg = lane >> 4, cc = lane & 15;

  // ---- stage: fields -> s_fld, stig ----
  if (half == 0){
    for (int j = 0; j < 9; j += 2){
      int id = cb[1+j] + j*1000;
      s_fld[j*132 + e] = embT[(size_t)id*128 + e];
    }
    float a0 = ub[e];
    for (int k = 0; k < 23; ++k) a0 += num[(size_t)b*63 + k] * uW[e*23 + k];
    s_fld[9*132 + e] = a0;
  } else {
    for (int j = 1; j < 9; j += 2){
      int id = cb[1+j] + j*1000;
      s_fld[j*132 + e] = embT[(size_t)id*128 + e];
    }
    float a2 = ib[e];
    for (int k = 0; k < 40; ++k) a2 += num[(size_t)b*63 + 23 + k] * iW[e*40 + k];
    s_fld[10*132 + e] = a2;
  }
  if (tid < 48){
    int t = (tid/6)%T_;
    float stw = st_w[t*S_ + scen];
    float acc = gate_b[tid];
    for (int i = 0; i < 4; ++i){
      float sti = scen_emb[scen*4+i] * task_emb[t*4+i] * stw;
      acc += sti * gate_W[tid*132 + i];
    }
    s_stig[tid] = acc;
  }
  __syncthreads();

  // ---- build pe bf16 (iw applied in epilogue) ----
  for (int idx = tid; idx < 1760; idx += 256){
    int row = idx >> 5, q = idx & 31;
    float4 x = *(const float4*)&s_fld[PR[row]*132 + q*4];
    float4 y = *(const float4*)&s_fld[PC[row]*132 + q*4];
    ushort4 o;
    o.x = f2bf(x.x*y.x); o.y = f2bf(x.y*y.y); o.z = f2bf(x.z*y.z); o.w = f2bf(x.w*y.w);
    *(ushort4*)&s_peb[row*136 + q*4] = o;
  }
  __syncthreads();

  // ---- MFMA GEMM: C[64][64] = pe x Wu^T ----
  f32x4 acc0 = {0.f,0.f,0.f,0.f}, acc1 = acc0, acc2 = acc0, acc3 = acc0;
  {
    const int kb = cg * 8;
    #pragma unroll
    for (int ks = 0; ks < 4; ++ks){
      int ko = ks*32 + kb;
      bf16x8 bfr = *(const bf16x8*)&Wub[(w*16 + cc)*136 + ko];
      bf16x8 a0 = *(const bf16x8*)&s_peb[( 0 + cc)*136 + ko];
      bf16x8 a1 = *(const bf16x8*)&s_peb[(16 + cc)*136 + ko];
      bf16x8 a2 = *(const bf16x8*)&s_peb[(32 + cc)*136 + ko];
      bf16x8 a3 = *(const bf16x8*)&s_peb[(48 + cc)*136 + ko];
      acc0 = __builtin_amdgcn_mfma_f32_16x16x32_bf16(a0, bfr, acc0, 0, 0, 0);
      acc1 = __builtin_amdgcn_mfma_f32_16x16x32_bf16(a1, bfr, acc1, 0, 0, 0);
      acc2 = __builtin_amdgcn_mfma_f32_16x16x32_bf16(a2, bfr, acc2, 0, 0, 0);
      acc3 = __builtin_amdgcn_mfma_f32_16x16x32_bf16(a3, bfr, acc3, 0, 0, 0);
    }
  }
  __syncthreads();
  {
    const int col = w*16 + cc;
    const float bias = (col < 48) ? s_stig[col] : ((col < 62) ? sb_b[col-48] : 0.f);
    #pragma unroll
    for (int r = 0; r < 4; ++r){
      int row0 = cg*4 + r;
      float v0 = (r==0)?acc0.x:((r==1)?acc0.y:((r==2)?acc0.z:acc0.w));
      float v1 = (r==0)?acc1.x:((r==1)?acc1.y:((r==2)?acc1.z:acc1.w));
      float v2 = (r==0)?acc2.x:((r==1)?acc2.y:((r==2)?acc2.z:acc2.w));
      float v3 = (r==0)?acc3.x:((r==1)?acc3.y:((r==2)?acc3.z:acc3.w));
      s_C[(row0     )*65 + col] = v0*interact_w[row0     ] + bias;
      s_C[(row0 + 16)*65 + col] = v1*interact_w[row0 + 16] + bias;
      s_C[(row0 + 32)*65 + col] = v2*interact_w[row0 + 32] + bias;
      if (row0 + 48 < 55)
        s_C[(row0 + 48)*65 + col] = v3*interact_w[row0 + 48] + bias;
    }
  }
  __syncthreads();
  for (int o = tid; o < 880; o += 256){
    int f = o >> 4, j = o & 15;
    float acc = shexp_b[j];
    const float* ein = &s_C[f*65 + 48];
    const float* wp = &shexp_W[j*14];
    for (int i = 0; i < 14; ++i) acc += ein[i] * wp[i];
    s_sh[f*17 + j] = acc;
  }
  __syncthreads();
  for (int task = tid; task < 440; task += 256){
    int st = task / 55, f = task % 55;
    float ein[14];
    for (int i = 0; i < 14; ++i) ein[i] = s_C[f*65 + 48 + i];
    float lg[6], mx = -1e30f;
    for (int g = 0; g < 6; ++g){ lg[g] = s_C[f*65 + st*6 + g]; mx = fmaxf(mx, lg[g]); }
    float sum = 0.f;
    for (int g = 0; g < 6; ++g){ lg[g] = __expf(lg[g]-mx); sum += lg[g]; }
    float inv = 1.f/sum;
    float wv[4] = {0,0,0,0};
    for (int g = 0; g < 4; ++g){
      float gg = lg[g]*inv;
      for (int m = 0; m < 4; ++m) wv[m] += gg * s_sh[f*17 + g*4 + m];
    }
    for (int ee = 0; ee < 2; ++ee){
      float gg = lg[4+ee]*inv;
      for (int m = 0; m < 4; ++m){
        float acc = spexp_b[(st*2+ee)*4+m];
        const float* wp = spexp_W + ((st*2+ee)*4+m)*14;
        for (int i = 0; i < 14; ++i) acc += ein[i] * wp[i];
        wv[m] += gg*acc;
      }
    }
    ushort4 o4;
    o4.x = f2bf(wv[0]); o4.y = f2bf(wv[1]); o4.z = f2bf(wv[2]); o4.w = f2bf(wv[3]);
    *(ushort4*)&w_gb[((size_t)b*8 + st)*224 + f*4] = o4;
  }
  if (tid < 8){
    ushort4 z = {0,0,0,0};
    *(ushort4*)&w_gb[((size_t)b*8 + tid)*224 + 220] = z;
  }
  __syncthreads();

  // ---- moe2: gather lfields as bf16 + stig2 ----
  if (half == 0){
    for (int j = 0; j < 9; j += 2){
      int id = cb[1+j] + j*1000;
      s_lfb[j*136 + e] = f2bf(linT[(size_t)id*128 + e]);
    }
    float a1 = ulb[e];
    for (int k = 0; k < 23; ++k) a1 += num[(size_t)b*63 + k] * ulW[e*23 + k];
    s_lfb[9*136 + e] = f2bf(a1);
  } else {
    for (int j = 1; j < 9; j += 2){
      int id = cb[1+j] + j*1000;
      s_lfb[j*136 + e] = f2bf(linT[(size_t)id*128 + e]);
    }
    float a3 = ilb[e];
    for (int k = 0; k < 40; ++k) a3 += num[(size_t)b*63 + 23 + k] * ilW[e*40 + k];
    s_lfb[10*136 + e] = f2bf(a3);
  }
  if (tid < 48){
    int t = (tid/6)%T_;
    float stw = st_w[t*S_ + scen];
    float acc = lgate_b[tid];
    for (int i = 0; i < 4; ++i){
      float sti = scen_emb[scen*4+i] * task_emb[t*4+i] * stw;
      acc += sti * lgate_W[tid*132 + i];
    }
    m2_stig[tid] = acc;
  }
  __syncthreads();
  {
    f32x4 macc = {0.f,0.f,0.f,0.f};
    const int kb = cg * 8;
    #pragma unroll
    for (int ks = 0; ks < 4; ++ks){
      int ko = ks*32 + kb;
      bf16x8 bfr = *(const bf16x8*)&lWub[(w*16 + cc)*136 + ko];
      bf16x8 av  = *(const bf16x8*)&s_lfb[cc*136 + ko];
      macc = __builtin_amdgcn_mfma_f32_16x16x32_bf16(av, bfr, macc, 0, 0, 0);
    }
    const int col = w*16 + cc;
    const float bias = (col < 48) ? m2_stig[col] : ((col < 62) ? lsb_b[col-48] : 0.f);
    #pragma unroll
    for (int r = 0; r < 4; ++r){
      int row = cg*4 + r;
      if (row < 11){
        float v = (r==0)?macc.x:((r==1)?macc.y:((r==2)?macc.z:macc.w));
        m2_C[row*65 + col] = v + bias;
      }
    }
  }
  __syncthreads();
  if (tid < 176){
    int f = tid >> 4, j = tid & 15;
    float acc = lshexp_b[j];
    const float* ein = &m2_C[f*65 + 48];
    for (int i = 0; i < 14; ++i) acc += ein[i] * lshexp_W[j*14+i];
    m2_sh[f*17 + j] = acc;
  }
  __syncthreads();
  if (tid < 88){
    int st = tid / 11, f = tid % 11;
    float ein[14];
    for (int i = 0; i < 14; ++i) ein[i] = m2_C[f*65 + 48 + i];
    float lg[6], mx = -1e30f;
    for (int g = 0; g < 6; ++g){ lg[g] = m2_C[f*65 + st*6 + g]; mx = fmaxf(mx, lg[g]); }
    float sum = 0.f;
    for (int g = 0; g < 6; ++g){ lg[g] = __expf(lg[g]-mx); sum += lg[g]; }
    float inv = 1.f/sum;
    float wv[4] = {0,0,0,0};
    for (int g = 0; g < 4; ++g){
      float gg = lg[g]*inv;
      for (int m = 0; m < 4; ++m) wv[m] += gg * m2_sh[f*17 + g*4 + m];
    }
    for (int ee = 0; ee < 2; ++ee){
      float gg = lg[4+ee]*inv;
      for (int m = 0; m < 4; ++m){
        float acc = lspexp_b[(st*2+ee)*4+m];
        const float* wp = lspexp_W + ((st*2+ee)*4+m)*14;
        for (int i = 0; i < 14; ++i) acc += ein[i] * wp[i];
        wv[m] += gg*acc;
      }
    }
    float4 o4; o4.x = wv[0]; o4.y = wv[1]; o4.z = wv[2]; o4.w = wv[3];
    *(float4*)&m2_w[st*44 + f*4] = o4;
  }
  __syncthreads();
  if (tid < 88){
    int st = tid / 11, oo = tid % 11;
    float acc = ltower_b[st*11+oo];
    const float* tw = ltower_W + (st*11+oo)*44;
    const float* wp = m2_w + st*44;
    for (int i = 0; i < 44; ++i) acc += wp[i] * tw[i];
    lt1[(size_t)(st*11+oo)*B_ + b] = acc;
  }
}

// -------- mask MFMA GEMM: m1[st*55+row][b] = mWb x w_gb^T + mb --------------
// grid 512 = 8 st x 64 b-tiles(64). B tile (w_g rows) staged in LDS bf16
// [64][232]; A fragments from L2-resident mWb global. 4 waves x 4 row-tiles
// x 7 K-steps (K=224). Same fragment mapping as moe1 (validated).
__global__ __launch_bounds__(256) void k_mask(
    const unsigned short* __restrict__ w_gb, const unsigned short* __restrict__ mWb,
    const float* __restrict__ mask_b, float* __restrict__ m1)
{
  __shared__ unsigned short s_wb[64*232];
  const int tid = threadIdx.x;
  const int st = blockIdx.x >> 6, bt = blockIdx.x & 63;
  const int b0 = bt*64;
  const int w = tid >> 6, lane = tid & 63;
  const int cg = lane >> 4, cc = lane & 15;

  // stage w_g tile: 64 rows x 224 bf16 (28 x 16B chunks per row)
  for (int idx = tid; idx < 1792; idx += 256){
    int r = idx / 28, q = idx % 28;
    *(float4*)&s_wb[r*232 + q*8] =
        *(const float4*)&w_gb[(size_t)(b0+r)*1792 + st*224 + q*8];
  }
  __syncthreads();

  f32x4 acc0 = {0.f,0.f,0.f,0.f}, acc1 = acc0, acc2 = acc0, acc3 = acc0;
  const unsigned short* Ast = mWb + (size_t)st*64*224;
  {
    const int kb = cg * 8;
    #pragma unroll
    for (int ks = 0; ks < 7; ++ks){
      int ko = ks*32 + kb;
      bf16x8 bfr = *(const bf16x8*)&s_wb[(w*16 + cc)*232 + ko];
      bf16x8 a0 = *(const bf16x8*)&Ast[( 0 + cc)*224 + ko];
      bf16x8 a1 = *(const bf16x8*)&Ast[(16 + cc)*224 + ko];
      bf16x8 a2 = *(const bf16x8*)&Ast[(32 + cc)*224 + ko];
      bf16x8 a3 = *(const bf16x8*)&Ast[(48 + cc)*224 + ko];
      acc0 = __builtin_amdgcn_mfma_f32_16x16x32_bf16(a0, bfr, acc0, 0, 0, 0);
      acc1 = __builtin_amdgcn_mfma_f32_16x16x32_bf16(a1, bfr, acc1, 0, 0, 0);
      acc2 = __builtin_amdgcn_mfma_f32_16x16x32_bf16(a2, bfr, acc2, 0, 0, 0);
      acc3 = __builtin_amdgcn_mfma_f32_16x16x32_bf16(a3, bfr, acc3, 0, 0, 0);
    }
  }
  // epilogue: D col = b (b0 + w*16 + cc), row = tile + cg*4 + r
  {
    const int col = b0 + w*16 + cc;
    #pragma unroll
    for (int r = 0; r < 4; ++r){
      int row0 = cg*4 + r;
      float v0 = (r==0)?acc0.x:((r==1)?acc0.y:((r==2)?acc0.z:acc0.w));
      float v1 = (r==0)?acc1.x:((r==1)?acc1.y:((r==2)?acc1.z:acc1.w));
      float v2 = (r==0)?acc2.x:((r==1)?acc2.y:((r==2)?acc2.z:acc2.w));
      float v3 = (r==0)?acc3.x:((r==1)?acc3.y:((r==2)?acc3.z:acc3.w));
      m1[(size_t)(st*55 + row0     )*B_ + col] = v0 + mask_b[st*55 + row0     ];
      m1[(size_t)(st*55 + row0 + 16)*B_ + col] = v1 + mask_b[st*55 + row0 + 16];
      m1[(size_t)(st*55 + row0 + 32)*B_ + col] = v2 + mask_b[st*55 + row0 + 32];
      if (row0 + 48 < 55)
        m1[(size_t)(st*55 + row0 + 48)*B_ + col] = v3 + mask_b[st*55 + row0 + 48];
    }
  }
}

// -------- per-row batch stats (mean, rsqrt(var+eps)) ------------------------
__global__ __launch_bounds__(256) void k_stats(const float* __restrict__ x, float* __restrict__ stats){
  const int row = blockIdx.x, tid = threadIdx.x;
  const float* xr = x + (size_t)row*B_;
  float s = 0.f, s2 = 0.f;
  for (int i = tid; i < B_; i += 256){ float v = xr[i]; s += v; s2 += v*v; }
  for (int off = 32; off > 0; off >>= 1){ s += __shfl_down(s, off); s2 += __shfl_down(s2, off); }
  __shared__ float red[8];
  if ((tid & 63) == 0){ red[(tid>>6)*2] = s; red[(tid>>6)*2+1] = s2; }
  __syncthreads();
  if (tid == 0){
    float Ssum = red[0]+red[2]+red[4]+red[6], S2 = red[1]+red[3]+red[5]+red[7];
    float mean = Ssum*(1.f/B_), var = S2*(1.f/B_) - mean*mean;
    stats[row*2] = mean; stats[row*2+1] = rsqrtf(fmaxf(var, 0.f) + EPSf);
  }
}

// -------- fused stats for two row-batches -----------------------------------
__global__ __launch_bounds__(256) void k_stats2(const float* __restrict__ x1, const float* __restrict__ x2,
                                                int n1, float* __restrict__ st1o, float* __restrict__ st2o){
  const int row = blockIdx.x, tid = threadIdx.x;
  const float* xr; float* sto;
  if (row < n1){ xr = x1 + (size_t)row*B_; sto = st1o + row*2; }
  else { int r = row - n1; xr = x2 + (size_t)r*B_; sto = st2o + r*2; }
  float s = 0.f, s2 = 0.f;
  for (int i = tid; i < B_; i += 256){ float v = xr[i]; s += v; s2 += v*v; }
  for (int off = 32; off > 0; off >>= 1){ s += __shfl_down(s, off); s2 += __shfl_down(s2, off); }
  __shared__ float red[8];
  if ((tid & 63) == 0){ red[(tid>>6)*2] = s; red[(tid>>6)*2+1] = s2; }
  __syncthreads();
  if (tid == 0){
    float Ssum = red[0]+red[2]+red[4]+red[6], S2 = red[1]+red[3]+red[5]+red[7];
    float mean = Ssum*(1.f/B_), var = S2*(1.f/B_) - mean*mean;
    sto[0] = mean; sto[1] = rsqrtf(fmaxf(var, 0.f) + EPSf);
  }
}

// -------- interlinf+last1: bn/tanh/relu inter + softmax linf + W1 GEMM ------
__global__ __launch_bounds__(128) void k_interlinf(
    const int* __restrict__ cat, const float* __restrict__ num,
    const float* __restrict__ embT, const float* __restrict__ linT,
    const float* __restrict__ uW, const float* __restrict__ ub,
    const float* __restrict__ iW, const float* __restrict__ ib,
    const float* __restrict__ ulW, const float* __restrict__ ulb,
    const float* __restrict__ ilW, const float* __restrict__ ilb,
    const float* __restrict__ m1, const float* __restrict__ stm,
    const float* __restrict__ lt1, const float* __restrict__ stl,
    const float* __restrict__ att_W, const float* __restrict__ interact_w,
    const float* __restrict__ bias_p,
    const float* __restrict__ W1, const float* __restrict__ b1,
    float* __restrict__ h1)
{
  __shared__ float s_fld[NF_*E_];
  __shared__ float s_lf[NF_*E_];
  __shared__ float s_co[110];
  __shared__ float s_lw[22];
  __shared__ float s_h[512];
  const int b = blockIdx.x, e = threadIdx.x;
  const int* cb = cat + (size_t)b*10;
  const int scen = cb[0];

  for (int j = 0; j < 9; ++j){
    int id = cb[1+j] + j*1000;
    s_fld[j*E_+e] = embT[(size_t)id*128 + e];
    s_lf[j*E_+e]  = linT[(size_t)id*128 + e];
  }
  {
    float a0 = ub[e], a1 = ulb[e];
    for (int k = 0; k < 23; ++k){ float x = num[(size_t)b*63 + k]; a0 += x*uW[e*23+k]; a1 += x*ulW[e*23+k]; }
    s_fld[9*E_+e] = a0; s_lf[9*E_+e] = a1;
    float a2 = ib[e], a3 = ilb[e];
    for (int k = 0; k < 40; ++k){ float x = num[(size_t)b*63 + 23 + k]; a2 += x*iW[e*40+k]; a3 += x*ilW[e*40+k]; }
    s_fld[10*E_+e] = a2; s_lf[10*E_+e] = a3;
  }
  if (e < 110){
    int t = e/55, f = e%55, row = (scen*T_+t)*55 + f;
    float v = (m1[(size_t)row*B_+b] - stm[row*2]) * stm[row*2+1];
    v = fmaxf(tanhf(v), 0.f);
    s_co[e] = v * att_W[(scen*T_+t)*55 + f];
  }
  if (e < 22){
    int t = e/11, f = e%11, row = (scen*T_+t)*11 + f;
    s_lw[e] = (lt1[(size_t)row*B_+b] - stl[row*2]) * stl[row*2+1];
  }
  __syncthreads();
  if (e < 2){
    int t = e; float mx = -1e30f;
    for (int f = 0; f < 11; ++f) mx = fmaxf(mx, s_lw[t*11+f]);
    float sum = 0.f;
    for (int f = 0; f < 11; ++f){ float x = __expf(s_lw[t*11+f]-mx); s_lw[t*11+f] = x; sum += x; }
    float inv = 1.f/sum;
    for (int f = 0; f < 11; ++f) s_lw[t*11+f] *= inv;
  }
  __syncthreads();
  {
    float a0 = 0.f, a1 = 0.f;
    for (int f = 0; f < 55; ++f){
      float pe = s_fld[PR[f]*E_+e] * s_fld[PC[f]*E_+e] * interact_w[f];
      a0 += s_co[f]*pe; a1 += s_co[55+f]*pe;
    }
    s_h[0*256 + e] = a0;
    s_h[1*256 + e] = a1;
  }
  for (int t = 0; t < 2; ++t){
    float acc = bias_p[(size_t)(t*S_+scen)*E_ + e];
    for (int f = 0; f < 11; ++f) acc += s_lw[t*11+f] * s_lf[f*E_+e];
    s_h[t*256 + 128 + e] = acc;
  }
  __syncthreads();
  if (e < 80){
    int t = e / 40, o = e % 40;
    float acc = b1[t*40 + o];
    const float4* wr = (const float4*)(W1 + (size_t)(t*40 + o)*256);
    const float4* hh = (const float4*)(s_h + t*256);
    for (int i = 0; i < 64; ++i){
      float4 w = wr[i], h = hh[i];
      acc += h.x*w.x; acc += h.y*w.y; acc += h.z*w.z; acc += h.w*w.w;
    }
    h1[(size_t)(t*40 + o)*B_ + b] = acc;
  }
}

// -------- final MLP tail ----------------------------------------------------
__global__ __launch_bounds__(256) void k_last2(const float* __restrict__ h1, const float* __restrict__ st1,
    const float* __restrict__ W2, const float* __restrict__ b2v, float* __restrict__ h2){
  int bz = blockIdx.x, t = bz/16, bc = bz%16, tid = threadIdx.x, b = bc*256 + tid;
  __shared__ float s_w2[1280];
  for (int k = tid; k < 1280; k += 256) s_w2[k] = W2[t*1280 + k];
  __syncthreads();
  float hv[40];
  for (int i = 0; i < 40; ++i){
    int row = t*40 + i;
    hv[i] = fmaxf((h1[(size_t)row*B_+b] - st1[row*2]) * st1[row*2+1], 0.f);
  }
  for (int o = 0; o < 32; ++o){
    float acc = b2v[t*32+o];
    for (int i = 0; i < 40; ++i) acc += hv[i] * s_w2[o*40+i];
    h2[(size_t)(t*32+o)*B_ + b] = acc;
  }
}

__global__ __launch_bounds__(256) void k_last3(const float* __restrict__ h2, const float* __restrict__ st2,
    const float* __restrict__ W3, const float* __restrict__ b3v, float* __restrict__ h3){
  int bz = blockIdx.x, t = bz/16, bc = bz%16, tid = threadIdx.x, b = bc*256 + tid;
  __shared__ float s_w3[256];
  if (tid < 256) s_w3[tid] = W3[t*256 + tid];
  __syncthreads();
  float hv[32];
  for (int i = 0; i < 32; ++i){
    int row = t*32 + i;
    hv[i] = fmaxf((h2[(size_t)row*B_+b] - st2[row*2]) * st2[row*2+1], 0.f);
  }
  for (int o = 0; o < 8; ++o){
    float acc = b3v[t*8+o];
    for (int i = 0; i < 32; ++i) acc += hv[i] * s_w3[o*32+i];
    h3[(size_t)(t*8+o)*B_ + b] = acc;
  }
}

__global__ __launch_bounds__(256) void k_out(const float* __restrict__ h3, const float* __restrict__ st3,
    const float* __restrict__ W4, const float* __restrict__ b4v, float* __restrict__ out){
  int idx = blockIdx.x*256 + threadIdx.x;
  int t = idx / B_, b = idx % B_;
  float acc = b4v[t];
  for (int i = 0; i < 8; ++i){
    int row = t*8 + i;
    float v = fmaxf((h3[(size_t)row*B_+b] - st3[row*2]) * st3[row*2+1], 0.f);
    acc += v * W4[t*8+i];
  }
  out[idx] = 1.f/(1.f + __expf(-acc));
}

extern "C" void kernel_launch(void* const* d_in, const int* in_sizes, int n_in,
                              void* d_out, int out_size, void* d_ws, size_t ws_size,
                              hipStream_t stream)
{
  const int*   cat      = (const int*)  d_in[0];
  const float* num      = (const float*)d_in[1];
  const float* embT     = (const float*)d_in[2];
  const float* linT     = (const float*)d_in[3];
  const float* uW = (const float*)d_in[4];  const float* ub = (const float*)d_in[5];
  const float* iW = (const float*)d_in[6];  const float* ib = (const float*)d_in[7];
  const float* ulW = (const float*)d_in[8]; const float* ulb = (const float*)d_in[9];
  const float* ilW = (const float*)d_in[10];const float* ilb = (const float*)d_in[11];
  const float* scen_emb = (const float*)d_in[12];
  const float* task_emb = (const float*)d_in[13];
  const float* st_w     = (const float*)d_in[14];
  const float* interact_w=(const float*)d_in[15];
  const float* sbW = (const float*)d_in[16]; const float* sbb = (const float*)d_in[17];
  const float* lsbW = (const float*)d_in[18];const float* lsbb = (const float*)d_in[19];
  const float* shW = (const float*)d_in[20]; const float* shb = (const float*)d_in[21];
  const float* spW = (const float*)d_in[22]; const float* spb = (const float*)d_in[23];
  const float* lshW = (const float*)d_in[24];const float* lshb = (const float*)d_in[25];
  const float* lspW = (const float*)d_in[26];const float* lspb = (const float*)d_in[27];
  const float* gW = (const float*)d_in[28];  const float* gb = (const float*)d_in[29];
  const float* lgW = (const float*)d_in[30]; const float* lgb = (const float*)d_in[31];
  const float* mW = (const float*)d_in[32];  const float* mb = (const float*)d_in[33];
  const float* attW = (const float*)d_in[34];
  const float* ltW = (const float*)d_in[35]; const float* ltb = (const float*)d_in[36];
  const float* biasP = (const float*)d_in[37];
  const float* W1 = (const float*)d_in[38];  const float* b1 = (const float*)d_in[39];
  const float* W2 = (const float*)d_in[40];  const float* b2v = (const float*)d_in[41];
  const float* W3 = (const float*)d_in[42];  const float* b3v = (const float*)d_in[43];
  const float* W4 = (const float*)d_in[44];  const float* b4v = (const float*)d_in[45];
  float* out = (float*)d_out;

  float* ws = (float*)d_ws;
  size_t o = 0;
  float* Wub  = ws + o; o += 4352;    // bf16 64x136
  float* lWub = ws + o; o += 4352;    // bf16 64x136
  float* mWb  = ws + o; o += 57344;   // bf16 8x64x224
  float* w_gb = ws + o; o += 3670016; // bf16 4096x8x224
  float* m1   = ws + o; o += (size_t)440*B_;
  float* stm  = ws + o; o += 880;
  float* lt1  = ws + o; o += (size_t)88*B_;
  float* stl  = ws + o; o += 176;
  float* h1   = ws + o; o += (size_t)80*B_;
  float* st1  = ws + o; o += 160;
  float* h2   = ws + o; o += (size_t)64*B_;
  float* st2  = ws + o; o += 128;
  float* h3   = ws + o; o += (size_t)16*B_;
  float* st3  = ws + o; o += 32;

  k_prep<<<448, 256, 0, stream>>>(gW, lgW, sbW, lsbW, mW,
                                  (unsigned short*)Wub, (unsigned short*)lWub,
                                  (unsigned short*)mWb);
  k_moe12<<<B_, 256, 0, stream>>>(cat, num, embT, linT, uW, ub, iW, ib, ulW, ulb, ilW, ilb,
                                  scen_emb, task_emb, st_w, interact_w, sbb, shW, shb,
                                  spW, spb, gW, gb, (const unsigned short*)Wub,
                                  lsbb, lshW, lshb, lspW, lspb, lgW, lgb, ltW, ltb,
                                  (const unsigned short*)lWub, (unsigned short*)w_gb, lt1);
  k_mask<<<512, 256, 0, stream>>>((const unsigned short*)w_gb, (const unsigned short*)mWb, mb, m1);
  k_stats2<<<528, 256, 0, stream>>>(m1, lt1, 440, stm, stl);
  k_interlinf<<<B_, 128, 0, stream>>>(cat, num, embT, linT, uW, ub, iW, ib, ulW, ulb, ilW, ilb,
                                      m1, stm, lt1, stl, attW, interact_w, biasP,
                                      W1, b1, h1);
  k_stats<<<80, 256, 0, stream>>>(h1, st1);
  k_last2<<<32, 256, 0, stream>>>(h1, st1, W2, b2v, h2);
  k_stats<<<64, 256, 0, stream>>>(h2, st2);
  k_last3<<<32, 256, 0, stream>>>(h2, st2, W3, b3v, h3);
  k_stats<<<16, 256, 0, stream>>>(h3, st3);
  k_out<<<32, 256, 0, stream>>>(h3, st3, W4, b4v, out);
}